// Round 9
// baseline (481.798 us; speedup 1.0000x reference)
//
#include <hip/hip_runtime.h>

// ---------------------------------------------------------------------------
// HeteroGNN (GAT x3 + transform x2) on MI355X — Round 9.
// R8 post-mortem: 472us wall vs ~210us kernel sum -> ~10-12us per-dispatch
// fixed cost dominates (14 dispatches + memset). This round:
//  * mega-fusion 15 -> 7 dispatches (block-granular union kernels)
//  * dual-relation GEMM: Hcc+Hcio share staged x_cell (A read halved)
//  * scans rewritten for 256-thread blocks; memset folded into K1
//  * dest_agg / hist / scatter / gemv inner logic byte-identical to R8
// ---------------------------------------------------------------------------

#define NC   100000
#define NIO  2000
#define ECC  600000
#define ECIO 50000
#define EIOC 50000

#define PAD_CC   100352                  // 49*2048
#define PAD_IO   2048
#define NTOT_PAD (2 * PAD_CC + PAD_IO)   // 202752
#define SCAN_NBLK (NTOT_PAD / 2048)      // 99

// union grids
#define GB_PREP 320
#define GB_ZERO 198                      // 202752 ints / (256*4)
#define GB_DUAL 782                      // (NC+127)/128
#define GB_IOC  16                       // (NIO+127)/128
#define GB_GEMV 1024
#define GB_HIST 2735                     // (700000+255)/256
#define GB_AGGC 25000                    // NC/4 waves-per-dest
#define GB_AGGI 500
#define GB_TC   782
#define GB_TI   16

typedef unsigned short u16;
typedef short bf16x8 __attribute__((ext_vector_type(8)));
typedef float f32x4 __attribute__((ext_vector_type(4)));

static __device__ __forceinline__ u16 f2bf(float x) {  // RNE fp32->bf16 bits
  unsigned u = __float_as_uint(x);
  return (u16)((u + 0x7FFFu + ((u >> 16) & 1u)) >> 16);
}
static __device__ __forceinline__ float bf2f(u16 h) {
  return __uint_as_float(((unsigned)h) << 16);
}

// ===== GEMM building blocks (logic identical to R8) ==========================
static __device__ __forceinline__ void stage_A(const float* __restrict__ A, int M,
                                               int bm, int kt, int tid,
                                               u16* Ah, u16* Al) {
#pragma unroll
  for (int q = 0; q < 4; ++q) {
    int flat = q * 256 + tid;            // 1024 chunks of 8 floats
    int row = flat >> 3, kg = flat & 7;
    int grow = bm + row;
    float f[8];
    if (grow < M) {
      float4 v0 = *(const float4*)(A + (size_t)grow * 128 + kt * 64 + kg * 8);
      float4 v1 = *(const float4*)(A + (size_t)grow * 128 + kt * 64 + kg * 8 + 4);
      f[0] = v0.x; f[1] = v0.y; f[2] = v0.z; f[3] = v0.w;
      f[4] = v1.x; f[5] = v1.y; f[6] = v1.z; f[7] = v1.w;
    } else {
#pragma unroll
      for (int j = 0; j < 8; ++j) f[j] = 0.f;
    }
    union { bf16x8 v; u16 u[8]; } ph, pl;
#pragma unroll
    for (int j = 0; j < 8; ++j) {
      u16 h = f2bf(f[j]);
      ph.u[j] = h;
      pl.u[j] = f2bf(f[j] - bf2f(h));
    }
    int off = row * 64 + ((kg ^ (row & 7)) * 8);
    *(bf16x8*)(Ah + off) = ph.v;
    *(bf16x8*)(Al + off) = pl.v;
  }
}

static __device__ __forceinline__ void stage_W(const u16* __restrict__ WT, int kt,
                                               int tid, u16* Wh, u16* Wl) {
  const int4* sh = (const int4*)(WT + kt * 8192);
  const int4* sl = (const int4*)(WT + 16384 + kt * 8192);
#pragma unroll
  for (int q = 0; q < 4; ++q) {
    int idx = q * 256 + tid;
    ((int4*)Wh)[idx] = sh[idx];
    ((int4*)Wl)[idx] = sl[idx];
  }
}

static __device__ __forceinline__ void mfma_tile(const u16* Ah, const u16* Al,
                                                 const u16* Wh, const u16* Wl,
                                                 int qm, int qn, int l15, int l4,
                                                 f32x4 (&acc)[4][4]) {
#pragma unroll
  for (int kk = 0; kk < 2; ++kk) {
    bf16x8 ah[4], al[4], bh[4], bl[4];
#pragma unroll
    for (int mi = 0; mi < 4; ++mi) {
      int row = qm * 64 + mi * 16 + l15;
      int off = row * 64 + (((kk * 4 + l4) ^ (row & 7)) * 8);
      ah[mi] = *(const bf16x8*)(Ah + off);
      al[mi] = *(const bf16x8*)(Al + off);
    }
#pragma unroll
    for (int ni = 0; ni < 4; ++ni) {
      int n = qn * 64 + ni * 16 + l15;
      int off = n * 64 + (((kk * 4 + l4) ^ (n & 7)) * 8);
      bh[ni] = *(const bf16x8*)(Wh + off);
      bl[ni] = *(const bf16x8*)(Wl + off);
    }
#pragma unroll
    for (int mi = 0; mi < 4; ++mi)
#pragma unroll
      for (int ni = 0; ni < 4; ++ni) {
        acc[mi][ni] = __builtin_amdgcn_mfma_f32_16x16x32_bf16(
            ah[mi], bh[ni], acc[mi][ni], 0, 0, 0);
        acc[mi][ni] = __builtin_amdgcn_mfma_f32_16x16x32_bf16(
            ah[mi], bl[ni], acc[mi][ni], 0, 0, 0);
        acc[mi][ni] = __builtin_amdgcn_mfma_f32_16x16x32_bf16(
            al[mi], bh[ni], acc[mi][ni], 0, 0, 0);
      }
  }
}

// D layout: col = lane&15, row = (lane>>4)*4 + reg   [guide-verified]
static __device__ void epilogue1(f32x4 (&acc)[4][4], int bm, int M,
                                 float* __restrict__ Out,
                                 const float* __restrict__ as_vec, float* __restrict__ als,
                                 const float* __restrict__ ad_vec, float* __restrict__ ald) {
  const int tid = threadIdx.x, lane = tid & 63, wv = tid >> 6;
  const int qm = wv >> 1, qn = wv & 1, l15 = lane & 15, l4 = lane >> 4;
#pragma unroll
  for (int mi = 0; mi < 4; ++mi)
#pragma unroll
    for (int ni = 0; ni < 4; ++ni)
#pragma unroll
      for (int r = 0; r < 4; ++r) {
        int grow = bm + qm * 64 + mi * 16 + l4 * 4 + r;
        if (grow < M)
          Out[(size_t)grow * 128 + qn * 64 + ni * 16 + l15] = acc[mi][ni][r];
      }
  float asv[4], adv[4];
#pragma unroll
  for (int ni = 0; ni < 4; ++ni) {
    asv[ni] = as_vec[qn * 64 + ni * 16 + l15];
    adv[ni] = (ald != nullptr) ? ad_vec[qn * 64 + ni * 16 + l15] : 0.f;
  }
#pragma unroll
  for (int mi = 0; mi < 4; ++mi)
#pragma unroll
    for (int r = 0; r < 4; ++r) {
      float s0 = acc[mi][0][r] * asv[0] + acc[mi][1][r] * asv[1];
      float s1 = acc[mi][2][r] * asv[2] + acc[mi][3][r] * asv[3];
      float t0 = acc[mi][0][r] * adv[0] + acc[mi][1][r] * adv[1];
      float t1 = acc[mi][2][r] * adv[2] + acc[mi][3][r] * adv[3];
#pragma unroll
      for (int off = 1; off < 16; off <<= 1) {
        s0 += __shfl_xor(s0, off);
        s1 += __shfl_xor(s1, off);
        t0 += __shfl_xor(t0, off);
        t1 += __shfl_xor(t1, off);
      }
      if (l15 == 0) {
        int grow = bm + qm * 64 + mi * 16 + l4 * 4 + r;
        if (grow < M) {
          als[(size_t)grow * 4 + qn * 2]     = s0;
          als[(size_t)grow * 4 + qn * 2 + 1] = s1;
          if (ald != nullptr) {
            ald[(size_t)grow * 4 + qn * 2]     = t0;
            ald[(size_t)grow * 4 + qn * 2 + 1] = t1;
          }
        }
      }
    }
}

static __device__ void epilogue2(f32x4 (&acc)[4][4], int bm, int M,
                                 const float* __restrict__ A, float* __restrict__ Out,
                                 const float* __restrict__ bt, const float* __restrict__ gv_,
                                 const float* __restrict__ bev, u16* smem) {
  const int tid = threadIdx.x, lane = tid & 63, wv = tid >> 6;
  const int qm = wv >> 1, qn = wv & 1, l15 = lane & 15, l4 = lane >> 4;
  float btv[4], gvv[4], bevv[4];
#pragma unroll
  for (int ni = 0; ni < 4; ++ni) {
    int col = qn * 64 + ni * 16 + l15;
    btv[ni] = bt[col]; gvv[ni] = gv_[col]; bevv[ni] = bev[col];
  }
  float* part = (float*)(smem + 16384);  // reuse W area: [128 rows][2 qn][2]
#pragma unroll
  for (int mi = 0; mi < 4; ++mi)
#pragma unroll
    for (int r = 0; r < 4; ++r) {
      float hs = 0.f, hss = 0.f;
#pragma unroll
      for (int ni = 0; ni < 4; ++ni) {
        float hv = acc[mi][ni][r] + btv[ni];
        hs += hv; hss += hv * hv;
      }
#pragma unroll
      for (int off = 1; off < 16; off <<= 1) {
        hs += __shfl_xor(hs, off);
        hss += __shfl_xor(hss, off);
      }
      if (l15 == 0) {
        int rl = qm * 64 + mi * 16 + l4 * 4 + r;
        part[rl * 4 + qn * 2]     = hs;
        part[rl * 4 + qn * 2 + 1] = hss;
      }
    }
  __syncthreads();
#pragma unroll
  for (int mi = 0; mi < 4; ++mi)
#pragma unroll
    for (int r = 0; r < 4; ++r) {
      int rl = qm * 64 + mi * 16 + l4 * 4 + r;
      int grow = bm + rl;
      float s  = part[rl * 4] + part[rl * 4 + 2];
      float ss = part[rl * 4 + 1] + part[rl * 4 + 3];
      float mu = s * (1.f / 128.f);
      float var = ss * (1.f / 128.f) - mu * mu;
      float rs = rsqrtf(var + 1e-5f);
      if (grow < M) {
#pragma unroll
        for (int ni = 0; ni < 4; ++ni) {
          int col = qn * 64 + ni * 16 + l15;
          float y = A[(size_t)grow * 128 + col];
          float hv = acc[mi][ni][r] + btv[ni];
          float hn = (hv - mu) * rs * gvv[ni] + bevv[ni];
          Out[(size_t)grow * 128 + col] = y + (hn > 0.f ? hn : 0.f);
        }
      }
    }
}

// single-relation GEMM body (MODE1: H+logits, MODE2: transform)
template <int MODE>
static __device__ void gemm_body(int bx, const float* __restrict__ A, int M,
                                 const u16* __restrict__ WT, float* __restrict__ Out,
                                 const float* as_vec, float* als,
                                 const float* ad_vec, float* ald,
                                 const float* bt, const float* gv_, const float* bev,
                                 u16* smem) {
  u16* Ah = smem;
  u16* Al = smem + 8192;
  u16* Wh = smem + 16384;
  u16* Wl = smem + 24576;
  const int tid = threadIdx.x, bm = bx * 128, lane = tid & 63, wv = tid >> 6;
  const int qm = wv >> 1, qn = wv & 1, l15 = lane & 15, l4 = lane >> 4;
  f32x4 acc[4][4];
#pragma unroll
  for (int mi = 0; mi < 4; ++mi)
#pragma unroll
    for (int ni = 0; ni < 4; ++ni) acc[mi][ni] = {0.f, 0.f, 0.f, 0.f};
  for (int kt = 0; kt < 2; ++kt) {
    stage_A(A, M, bm, kt, tid, Ah, Al);
    stage_W(WT, kt, tid, Wh, Wl);
    __syncthreads();
    mfma_tile(Ah, Al, Wh, Wl, qm, qn, l15, l4, acc);
    __syncthreads();
  }
  if (MODE == 1) epilogue1(acc, bm, M, Out, as_vec, als, ad_vec, ald);
  else           epilogue2(acc, bm, M, A, Out, bt, gv_, bev, smem);
}

// dual-relation GEMM body: A staged once, two W images (cc then cio)
static __device__ void gemm_dual_body(int bx, const float* __restrict__ A, int M,
                                      const u16* __restrict__ WT0, const u16* __restrict__ WT1,
                                      float* __restrict__ H0, float* __restrict__ H1,
                                      const float* as0, float* als0,
                                      const float* ad0, float* ald0,
                                      const float* as1, float* als1, u16* smem) {
  u16* Ah = smem;
  u16* Al = smem + 8192;
  u16* Wh = smem + 16384;
  u16* Wl = smem + 24576;
  const int tid = threadIdx.x, bm = bx * 128, lane = tid & 63, wv = tid >> 6;
  const int qm = wv >> 1, qn = wv & 1, l15 = lane & 15, l4 = lane >> 4;
  f32x4 acc0[4][4], acc1[4][4];
#pragma unroll
  for (int mi = 0; mi < 4; ++mi)
#pragma unroll
    for (int ni = 0; ni < 4; ++ni) {
      acc0[mi][ni] = {0.f, 0.f, 0.f, 0.f};
      acc1[mi][ni] = {0.f, 0.f, 0.f, 0.f};
    }
  for (int kt = 0; kt < 2; ++kt) {
    stage_A(A, M, bm, kt, tid, Ah, Al);
    stage_W(WT0, kt, tid, Wh, Wl);
    __syncthreads();
    mfma_tile(Ah, Al, Wh, Wl, qm, qn, l15, l4, acc0);
    __syncthreads();                      // done reading W0
    stage_W(WT1, kt, tid, Wh, Wl);
    __syncthreads();
    mfma_tile(Ah, Al, Wh, Wl, qm, qn, l15, l4, acc1);
    __syncthreads();                      // done reading A + W1 (next kt restages)
  }
  epilogue1(acc0, bm, M, H0, as0, als0, ad0, ald0);
  epilogue1(acc1, bm, M, H1, as1, als1, nullptr, nullptr);
}

// ===== K1: prep_w union zero-counters =======================================
__global__ __launch_bounds__(256) void k1_prep(
    const float* __restrict__ W0, const float* __restrict__ W1,
    const float* __restrict__ W2, const float* __restrict__ W3,
    const float* __restrict__ W4, u16* __restrict__ wt,
    const float* __restrict__ ad_ioc, const float* __restrict__ ad_cio,
    float* __restrict__ Vd_ioc, float* __restrict__ Vd_cio,
    int* __restrict__ cnt_all) {
  int b = blockIdx.x;
  if (b < GB_PREP) {
    int t = b * 256 + threadIdx.x;       // 81920 threads
    int mat = t >> 14, e = t & 16383;
    int k = e >> 7, n = e & 127;
    const float* W = (mat == 0) ? W0 : (mat == 1) ? W1 : (mat == 2) ? W2
                   : (mat == 3) ? W3 : W4;
    float x = W[k * 128 + n];
    u16 h = f2bf(x);
    u16 l = f2bf(x - bf2f(h));
    int kt = k >> 6, kl = k & 63, kg = kl >> 3, j = kl & 7;
    int off = (kt * 128 + n) * 64 + ((kg ^ (n & 7)) * 8) + j;
    u16* base = wt + (size_t)mat * 32768;
    base[off] = h;
    base[16384 + off] = l;
    if (t < 1024) {  // Vd[k,h] = sum_c W[k, h*32+c]*ad[h*32+c]
      const float* Wv = (t < 512) ? W2 : W1;   // ioc then cio
      const float* ad = (t < 512) ? ad_ioc : ad_cio;
      float*       V  = (t < 512) ? Vd_ioc : Vd_cio;
      int i = t & 511, kk = i >> 2, hh = i & 3;
      float s = 0.f;
#pragma unroll
      for (int c = 0; c < 32; ++c) s += Wv[kk * 128 + hh * 32 + c] * ad[hh * 32 + c];
      V[kk * 4 + hh] = s;
    }
  } else {
    int i = (b - GB_PREP) * 256 + threadIdx.x;   // int4 index, 50688 total
    ((int4*)cnt_all)[i] = make_int4(0, 0, 0, 0);
  }
}

// ===== K2: dual GEMM (cc+cio) union ioc GEMM union gemv union hist ==========
__global__ __launch_bounds__(256) void k2_union(
    const float* __restrict__ x_cell, const float* __restrict__ x_io,
    const u16* __restrict__ WT_cc, const u16* __restrict__ WT_cio,
    const u16* __restrict__ WT_ioc,
    float* __restrict__ Hcc, float* __restrict__ Hcio, float* __restrict__ Hioc,
    const float* __restrict__ as_cc, float* __restrict__ als_cc,
    const float* __restrict__ ad_cc, float* __restrict__ ald_cc,
    const float* __restrict__ as_cio, float* __restrict__ als_cio,
    const float* __restrict__ as_ioc, float* __restrict__ als_ioc,
    const float* __restrict__ Vd_ioc, const float* __restrict__ Vd_cio,
    float* __restrict__ ald_ioc, float* __restrict__ ald_cio,
    const int* __restrict__ ei_cc, const int* __restrict__ ei_ioc,
    const int* __restrict__ ei_cio,
    int* __restrict__ c_cc, int* __restrict__ c_ioc, int* __restrict__ c_cio) {
  __shared__ u16 smem[32768];
  int b = blockIdx.x;
  if (b < GB_DUAL) {
    gemm_dual_body(b, x_cell, NC, WT_cc, WT_cio, Hcc, Hcio,
                   as_cc, als_cc, ad_cc, ald_cc, as_cio, als_cio, smem);
  } else if (b < GB_DUAL + GB_IOC) {
    gemm_body<1>(b - GB_DUAL, x_io, NIO, WT_ioc, Hioc, as_ioc, als_ioc,
                 nullptr, nullptr, nullptr, nullptr, nullptr, smem);
  } else if (b < GB_DUAL + GB_IOC + GB_GEMV) {
    // gemv: ald = x @ Vd for both node types (identical to R8 gemv_all)
    int lb = b - GB_DUAL - GB_IOC;
    int lane = threadIdx.x & 63;
    int wid  = (lb * 256 + (int)threadIdx.x) >> 6;
    int nw   = GB_GEMV * 4;
    for (int row = wid; row < NC + NIO; row += nw) {
      const float* xr; const float* Vd; float* o;
      if (row < NC) { xr = x_cell + (size_t)row * 128; Vd = Vd_ioc; o = ald_ioc + 4 * (size_t)row; }
      else { int r2 = row - NC; xr = x_io + (size_t)r2 * 128; Vd = Vd_cio; o = ald_cio + 4 * (size_t)r2; }
      float4 v0 = *(const float4*)(Vd + 8 * lane);
      float4 v1 = *(const float4*)(Vd + 8 * lane + 4);
      float2 xv = *(const float2*)(xr + 2 * lane);
      float p0 = xv.x * v0.x + xv.y * v1.x;
      float p1 = xv.x * v0.y + xv.y * v1.y;
      float p2 = xv.x * v0.z + xv.y * v1.z;
      float p3 = xv.x * v0.w + xv.y * v1.w;
#pragma unroll
      for (int off = 32; off >= 1; off >>= 1) {
        p0 += __shfl_xor(p0, off);
        p1 += __shfl_xor(p1, off);
        p2 += __shfl_xor(p2, off);
        p3 += __shfl_xor(p3, off);
      }
      if (lane == 0) *(float4*)o = make_float4(p0, p1, p2, p3);
    }
  } else {
    // hist (identical to R8 hist_all)
    int i = (b - GB_DUAL - GB_IOC - GB_GEMV) * 256 + threadIdx.x;
    if (i < ECC) atomicAdd(c_cc + ei_cc[ECC + i], 1);
    else if (i < ECC + EIOC) { int j = i - ECC; atomicAdd(c_ioc + ei_ioc[EIOC + j], 1); }
    else if (i < ECC + EIOC + ECIO) { int j = i - ECC - EIOC; atomicAdd(c_cio + ei_cio[ECIO + j], 1); }
  }
}

// ===== K3/K4: device-wide scan (256-thread blocks) ==========================
__global__ __launch_bounds__(256) void scan_p1(const int* __restrict__ cnt,
                                               int* __restrict__ bsum) {
  int b = blockIdx.x, t = threadIdx.x;
  const int4* p = (const int4*)(cnt + (size_t)b * 2048) + t * 2;
  int4 a = p[0], c = p[1];
  int s = a.x + a.y + a.z + a.w + c.x + c.y + c.z + c.w;
#pragma unroll
  for (int off = 1; off < 64; off <<= 1) s += __shfl_xor(s, off);
  __shared__ int ws_[4];
  if ((t & 63) == 0) ws_[t >> 6] = s;
  __syncthreads();
  if (t == 0) bsum[b] = ws_[0] + ws_[1] + ws_[2] + ws_[3];
}

__global__ __launch_bounds__(256) void scan_p3(
    const int* __restrict__ cnt, const int* __restrict__ bsum,
    int* __restrict__ roff_cc, int* __restrict__ wp_cc,
    int* __restrict__ roff_ioc, int* __restrict__ wp_ioc,
    int* __restrict__ roff_cio, int* __restrict__ wp_cio) {
  int b = blockIdx.x, t = threadIdx.x;
  __shared__ int topbase_s;
  __shared__ int wsum[4];
  if (t < 64) {  // exclusive sum of bsum[0..b) (99 <= 128 entries)
    int s = 0;
    if (t < b) s += bsum[t];
    if (t + 64 < b) s += bsum[t + 64];
#pragma unroll
    for (int off = 1; off < 64; off <<= 1) s += __shfl_xor(s, off);
    if (t == 0) topbase_s = s;
  }
  int gbase = b * 2048;
  const int4* p = (const int4*)(cnt + (size_t)gbase) + t * 2;
  int4 a = p[0], c = p[1];
  int cs[8] = {a.x, a.y, a.z, a.w, c.x, c.y, c.z, c.w};
  int s = cs[0] + cs[1] + cs[2] + cs[3] + cs[4] + cs[5] + cs[6] + cs[7];
  int lane = t & 63, wv = t >> 6;
  int inc = s;
#pragma unroll
  for (int off = 1; off < 64; off <<= 1) {
    int u = __shfl_up(inc, off);
    if (lane >= off) inc += u;
  }
  if (lane == 63) wsum[wv] = inc;
  __syncthreads();
  if (t == 0) {
    int run = 0;
#pragma unroll
    for (int i = 0; i < 4; ++i) { int x = wsum[i]; wsum[i] = run; run += x; }
  }
  __syncthreads();
  int excl = inc - s + wsum[wv] + topbase_s;

  int *roff, *wp;
  int rstart, rn, bsub;
  if (b < PAD_CC / 2048) {
    roff = roff_cc;  wp = wp_cc;  rstart = 0;          rn = NC;  bsub = 0;
  } else if (b < 2 * (PAD_CC / 2048)) {
    roff = roff_ioc; wp = wp_ioc; rstart = PAD_CC;     rn = NC;  bsub = ECC;
  } else {
    roff = roff_cio; wp = wp_cio; rstart = 2 * PAD_CC; rn = NIO; bsub = ECC + EIOC;
  }
  int li0 = gbase + t * 8 - rstart;
  int run = excl - bsub;
#pragma unroll
  for (int j = 0; j < 8; ++j) {
    if (li0 + j < rn) { roff[li0 + j] = run; wp[li0 + j] = run; }
    run += cs[j];
  }
  if (b == 0 && t == 0) {
    roff_cc[NC]   = ECC;
    roff_ioc[NC]  = EIOC;
    roff_cio[NIO] = ECIO;
  }
}

// ===== K5: scatter (identical to R8) ========================================
__global__ void scatter_all(const int* __restrict__ ei_cc, const int* __restrict__ ei_ioc,
                            const int* __restrict__ ei_cio,
                            int* __restrict__ wp_cc, int* __restrict__ wp_ioc,
                            int* __restrict__ wp_cio,
                            int* __restrict__ s_cc, int* __restrict__ s_ioc,
                            int* __restrict__ s_cio) {
  int i = blockIdx.x * blockDim.x + threadIdx.x;
  if (i < ECC) {
    int d = ei_cc[ECC + i];
    s_cc[atomicAdd(wp_cc + d, 1)] = ei_cc[i];
  } else if (i < ECC + EIOC) {
    int j = i - ECC;
    int d = ei_ioc[EIOC + j];
    s_ioc[atomicAdd(wp_ioc + d, 1)] = ei_ioc[j];
  } else if (i < ECC + EIOC + ECIO) {
    int j = i - ECC - EIOC;
    int d = ei_cio[ECIO + j];
    s_cio[atomicAdd(wp_cio + d, 1)] = ei_cio[j];
  }
}

// ===== K6: dest aggregation union (inner logic identical to R8) =============
static __device__ __forceinline__ float2 gat_contrib(
    int d, int lane, int h,
    const int* __restrict__ roff, const int* __restrict__ ssrc,
    const float* __restrict__ als, const float* __restrict__ ald,
    const float* __restrict__ Hs) {
  int base = roff[d], end = roff[d + 1];
  if (base == end) return make_float2(0.f, 0.f);
  float aldh = ald[4 * (size_t)d + h];
  float acc0 = 0.f, acc1 = 0.f, den = 0.f;
  for (int c0 = base; c0 < end; c0 += 64) {
    int idx  = c0 + lane;
    int my_s = (idx < end) ? ssrc[idx] : 0;
    int cn   = min(64, end - c0);
    for (int j = 0; j < cn; ++j) {
      int s = __shfl(my_s, j);
      float v = als[4 * (size_t)s + h] + aldh;
      v = v > 0.f ? v : 0.2f * v;
      float ex = __expf(v);
      den += ex;
      float2 hv = *(const float2*)(Hs + (size_t)s * 128 + 2 * lane);
      acc0 += ex * hv.x;
      acc1 += ex * hv.y;
    }
  }
  float inv = 1.f / (den + 1e-16f);
  return make_float2(acc0 * inv, acc1 * inv);
}

__global__ __launch_bounds__(256) void k_agg(
    const int* __restrict__ roff1, const int* __restrict__ ssrc1,
    const float* __restrict__ als1, const float* __restrict__ ald1,
    const float* __restrict__ H1, const float* __restrict__ b1,
    const int* __restrict__ roff2, const int* __restrict__ ssrc2,
    const float* __restrict__ als2, const float* __restrict__ ald2,
    const float* __restrict__ H2, const float* __restrict__ b2,
    float* __restrict__ Ycell,
    const int* __restrict__ roff3, const int* __restrict__ ssrc3,
    const float* __restrict__ als3, const float* __restrict__ ald3,
    const float* __restrict__ H3, const float* __restrict__ b3,
    float* __restrict__ Yio) {
  int b = blockIdx.x;
  int lane = threadIdx.x & 63;
  int h    = lane >> 4;
  if (b < GB_AGGC) {
    int wid = (b * 256 + (int)threadIdx.x) >> 6;       // 1 wave per cell dest
    float2 bb1 = *(const float2*)(b1 + 2 * lane);
    float2 bb2 = *(const float2*)(b2 + 2 * lane);
    for (int d = wid; d < NC; d += GB_AGGC * 4) {
      float2 c1 = gat_contrib(d, lane, h, roff1, ssrc1, als1, ald1, H1);
      float2 c2 = gat_contrib(d, lane, h, roff2, ssrc2, als2, ald2, H2);
      *(float2*)(Ycell + (size_t)d * 128 + 2 * lane) =
          make_float2(c1.x + c2.x + bb1.x + bb2.x, c1.y + c2.y + bb1.y + bb2.y);
    }
  } else {
    int wid = ((b - GB_AGGC) * 256 + (int)threadIdx.x) >> 6;
    float2 bb = *(const float2*)(b3 + 2 * lane);
    for (int d = wid; d < NIO; d += GB_AGGI * 4) {
      float2 c = gat_contrib(d, lane, h, roff3, ssrc3, als3, ald3, H3);
      *(float2*)(Yio + (size_t)d * 128 + 2 * lane) = make_float2(c.x + bb.x, c.y + bb.y);
    }
  }
}

// ===== K7: transform union ==================================================
__global__ __launch_bounds__(256) void k_transform(
    const float* __restrict__ Ycell, const u16* __restrict__ WT_tc,
    const float* __restrict__ bt_c, const float* __restrict__ g_c,
    const float* __restrict__ be_c, float* __restrict__ out_cell,
    const float* __restrict__ Yio, const u16* __restrict__ WT_ti,
    const float* __restrict__ bt_i, const float* __restrict__ g_i,
    const float* __restrict__ be_i, float* __restrict__ out_io) {
  __shared__ u16 smem[32768];
  int b = blockIdx.x;
  if (b < GB_TC) {
    gemm_body<2>(b, Ycell, NC, WT_tc, out_cell, nullptr, nullptr, nullptr,
                 nullptr, bt_c, g_c, be_c, smem);
  } else {
    gemm_body<2>(b - GB_TC, Yio, NIO, WT_ti, out_io, nullptr, nullptr, nullptr,
                 nullptr, bt_i, g_i, be_i, smem);
  }
}

// ---------------------------------------------------------------------------
extern "C" void kernel_launch(void* const* d_in, const int* in_sizes, int n_in,
                              void* d_out, int out_size, void* d_ws, size_t ws_size,
                              hipStream_t stream) {
  const float* x_cell = (const float*)d_in[0];
  const float* x_io   = (const float*)d_in[1];
  const int*   ei_cc  = (const int*)d_in[2];
  const int*   ei_cio = (const int*)d_in[3];
  const int*   ei_ioc = (const int*)d_in[4];
  const float* W_cc   = (const float*)d_in[5];
  const float* as_cc  = (const float*)d_in[6];
  const float* ad_cc  = (const float*)d_in[7];
  const float* b_cc   = (const float*)d_in[8];
  const float* W_cio  = (const float*)d_in[9];
  const float* as_cio = (const float*)d_in[10];
  const float* ad_cio = (const float*)d_in[11];
  const float* b_cio  = (const float*)d_in[12];
  const float* W_ioc  = (const float*)d_in[13];
  const float* as_ioc = (const float*)d_in[14];
  const float* ad_ioc = (const float*)d_in[15];
  const float* b_ioc  = (const float*)d_in[16];
  const float* Wt_cell = (const float*)d_in[17];
  const float* bt_cell = (const float*)d_in[18];
  const float* g_cell  = (const float*)d_in[19];
  const float* be_cell = (const float*)d_in[20];
  const float* Wt_io   = (const float*)d_in[21];
  const float* bt_io   = (const float*)d_in[22];
  const float* g_io    = (const float*)d_in[23];
  const float* be_io   = (const float*)d_in[24];

  float* out_cell = (float*)d_out;
  float* out_io   = (float*)d_out + (size_t)NC * 128;

  // ----- workspace layout (identical to R8) -----
  float* w = (float*)d_ws;
  size_t o = 0;
  float* Hcc     = w + o; o += (size_t)NC * 128;
  float* Hcio    = w + o; o += (size_t)NC * 128;
  float* Hioc    = w + o; o += (size_t)NIO * 128;
  float* Ycell   = w + o; o += (size_t)NC * 128;
  float* Yio     = w + o; o += (size_t)NIO * 128;
  float* als_cc  = w + o; o += (size_t)NC * 4;
  float* ald_cc  = w + o; o += (size_t)NC * 4;
  float* als_cio = w + o; o += (size_t)NC * 4;
  float* ald_ioc = w + o; o += (size_t)NC * 4;
  float* als_ioc = w + o; o += (size_t)NIO * 4;
  float* ald_cio = w + o; o += (size_t)NIO * 4;
  float* Vd_ioc  = w + o; o += 512;
  float* Vd_cio  = w + o; o += 512;
  u16* wt_base   = (u16*)(w + o); o += 81920;   // 5 mats x 32768 u16 (hi|lo)
  int* ib = (int*)(w + o);
  size_t io_ = 0;
  int* cnt_all  = ib + io_; io_ += NTOT_PAD;
  int* cnt_cc   = cnt_all;
  int* cnt_ioc  = cnt_all + PAD_CC;
  int* cnt_cio  = cnt_all + 2 * PAD_CC;
  int* bsum     = ib + io_; io_ += 128;
  int* roff_cc  = ib + io_; io_ += NC + 1;
  int* wp_cc    = ib + io_; io_ += NC;
  int* roff_ioc = ib + io_; io_ += NC + 1;
  int* wp_ioc   = ib + io_; io_ += NC;
  int* roff_cio = ib + io_; io_ += NIO + 1;
  int* wp_cio   = ib + io_; io_ += NIO;
  int* ssrc_cc  = ib + io_; io_ += ECC;
  int* ssrc_ioc = ib + io_; io_ += EIOC;
  int* ssrc_cio = ib + io_; io_ += ECIO;

  u16* WT_cc  = wt_base;
  u16* WT_cio = wt_base + 32768;
  u16* WT_ioc = wt_base + 2 * 32768;
  u16* WT_tc  = wt_base + 3 * 32768;
  u16* WT_ti  = wt_base + 4 * 32768;

  // K1: W prep + Vd + counter zeroing
  k1_prep<<<GB_PREP + GB_ZERO, 256, 0, stream>>>(
      W_cc, W_cio, W_ioc, Wt_cell, Wt_io, wt_base,
      ad_ioc, ad_cio, Vd_ioc, Vd_cio, cnt_all);

  // K2: dual GEMM (cc+cio) || ioc GEMM || gemv || hist
  k2_union<<<GB_DUAL + GB_IOC + GB_GEMV + GB_HIST, 256, 0, stream>>>(
      x_cell, x_io, WT_cc, WT_cio, WT_ioc, Hcc, Hcio, Hioc,
      as_cc, als_cc, ad_cc, ald_cc, as_cio, als_cio, as_ioc, als_ioc,
      Vd_ioc, Vd_cio, ald_ioc, ald_cio,
      ei_cc, ei_ioc, ei_cio, cnt_cc, cnt_ioc, cnt_cio);

  // K3/K4: device-wide scan
  scan_p1<<<SCAN_NBLK, 256, 0, stream>>>(cnt_all, bsum);
  scan_p3<<<SCAN_NBLK, 256, 0, stream>>>(cnt_all, bsum, roff_cc, wp_cc,
                                         roff_ioc, wp_ioc, roff_cio, wp_cio);

  // K5: scatter
  scatter_all<<<GB_HIST, 256, 0, stream>>>(
      ei_cc, ei_ioc, ei_cio, wp_cc, wp_ioc, wp_cio, ssrc_cc, ssrc_ioc, ssrc_cio);

  // K6: per-dest aggregation (cell || io)
  k_agg<<<GB_AGGC + GB_AGGI, 256, 0, stream>>>(
      roff_cc, ssrc_cc, als_cc, ald_cc, Hcc, b_cc,
      roff_ioc, ssrc_ioc, als_ioc, ald_ioc, Hioc, b_ioc, Ycell,
      roff_cio, ssrc_cio, als_cio, ald_cio, Hcio, b_cio, Yio);

  // K7: transform (cell || io) into d_out
  k_transform<<<GB_TC + GB_TI, 256, 0, stream>>>(
      Ycell, WT_tc, bt_cell, g_cell, be_cell, out_cell,
      Yio, WT_ti, bt_io, g_io, be_io, out_io);
}

// Round 10
// 467.990 us; speedup vs baseline: 1.0295x; 1.0295x over previous
//
#include <hip/hip_runtime.h>

// ---------------------------------------------------------------------------
// HeteroGNN (GAT x3 + transform x2) on MI355X — Round 10.
// R9 post-mortem: k2_union 170us @ 10.9% occupancy — union kernel forced
// no-LDS gemv/hist branches under the GEMM's 64KB-LDS/168-VGPR footprint
// (2 blocks/CU). Fix: split by RESOURCE CLASS:
//   K2a = dual GEMM (cc+cio) U ioc GEMM   (64KB LDS class)
//   K2b = gemv U hist                      (no-LDS high-occupancy class)
// Everything else identical to R9. 8 dispatches.
// ---------------------------------------------------------------------------

#define NC   100000
#define NIO  2000
#define ECC  600000
#define ECIO 50000
#define EIOC 50000

#define PAD_CC   100352                  // 49*2048
#define PAD_IO   2048
#define NTOT_PAD (2 * PAD_CC + PAD_IO)   // 202752
#define SCAN_NBLK (NTOT_PAD / 2048)      // 99

// grids
#define GB_PREP 320
#define GB_ZERO 198                      // 202752 ints / (256*4)
#define GB_DUAL 782                      // (NC+127)/128
#define GB_IOC  16                       // (NIO+127)/128
#define GB_GEMV 1024
#define GB_HIST 2735                     // (700000+255)/256
#define GB_AGGC 25000                    // NC/4 waves-per-dest
#define GB_AGGI 500
#define GB_TC   782
#define GB_TI   16

typedef unsigned short u16;
typedef short bf16x8 __attribute__((ext_vector_type(8)));
typedef float f32x4 __attribute__((ext_vector_type(4)));

static __device__ __forceinline__ u16 f2bf(float x) {  // RNE fp32->bf16 bits
  unsigned u = __float_as_uint(x);
  return (u16)((u + 0x7FFFu + ((u >> 16) & 1u)) >> 16);
}
static __device__ __forceinline__ float bf2f(u16 h) {
  return __uint_as_float(((unsigned)h) << 16);
}

// ===== GEMM building blocks (logic identical to R8/R9) =======================
static __device__ __forceinline__ void stage_A(const float* __restrict__ A, int M,
                                               int bm, int kt, int tid,
                                               u16* Ah, u16* Al) {
#pragma unroll
  for (int q = 0; q < 4; ++q) {
    int flat = q * 256 + tid;            // 1024 chunks of 8 floats
    int row = flat >> 3, kg = flat & 7;
    int grow = bm + row;
    float f[8];
    if (grow < M) {
      float4 v0 = *(const float4*)(A + (size_t)grow * 128 + kt * 64 + kg * 8);
      float4 v1 = *(const float4*)(A + (size_t)grow * 128 + kt * 64 + kg * 8 + 4);
      f[0] = v0.x; f[1] = v0.y; f[2] = v0.z; f[3] = v0.w;
      f[4] = v1.x; f[5] = v1.y; f[6] = v1.z; f[7] = v1.w;
    } else {
#pragma unroll
      for (int j = 0; j < 8; ++j) f[j] = 0.f;
    }
    union { bf16x8 v; u16 u[8]; } ph, pl;
#pragma unroll
    for (int j = 0; j < 8; ++j) {
      u16 h = f2bf(f[j]);
      ph.u[j] = h;
      pl.u[j] = f2bf(f[j] - bf2f(h));
    }
    int off = row * 64 + ((kg ^ (row & 7)) * 8);
    *(bf16x8*)(Ah + off) = ph.v;
    *(bf16x8*)(Al + off) = pl.v;
  }
}

static __device__ __forceinline__ void stage_W(const u16* __restrict__ WT, int kt,
                                               int tid, u16* Wh, u16* Wl) {
  const int4* sh = (const int4*)(WT + kt * 8192);
  const int4* sl = (const int4*)(WT + 16384 + kt * 8192);
#pragma unroll
  for (int q = 0; q < 4; ++q) {
    int idx = q * 256 + tid;
    ((int4*)Wh)[idx] = sh[idx];
    ((int4*)Wl)[idx] = sl[idx];
  }
}

static __device__ __forceinline__ void mfma_tile(const u16* Ah, const u16* Al,
                                                 const u16* Wh, const u16* Wl,
                                                 int qm, int qn, int l15, int l4,
                                                 f32x4 (&acc)[4][4]) {
#pragma unroll
  for (int kk = 0; kk < 2; ++kk) {
    bf16x8 ah[4], al[4], bh[4], bl[4];
#pragma unroll
    for (int mi = 0; mi < 4; ++mi) {
      int row = qm * 64 + mi * 16 + l15;
      int off = row * 64 + (((kk * 4 + l4) ^ (row & 7)) * 8);
      ah[mi] = *(const bf16x8*)(Ah + off);
      al[mi] = *(const bf16x8*)(Al + off);
    }
#pragma unroll
    for (int ni = 0; ni < 4; ++ni) {
      int n = qn * 64 + ni * 16 + l15;
      int off = n * 64 + (((kk * 4 + l4) ^ (n & 7)) * 8);
      bh[ni] = *(const bf16x8*)(Wh + off);
      bl[ni] = *(const bf16x8*)(Wl + off);
    }
#pragma unroll
    for (int mi = 0; mi < 4; ++mi)
#pragma unroll
      for (int ni = 0; ni < 4; ++ni) {
        acc[mi][ni] = __builtin_amdgcn_mfma_f32_16x16x32_bf16(
            ah[mi], bh[ni], acc[mi][ni], 0, 0, 0);
        acc[mi][ni] = __builtin_amdgcn_mfma_f32_16x16x32_bf16(
            ah[mi], bl[ni], acc[mi][ni], 0, 0, 0);
        acc[mi][ni] = __builtin_amdgcn_mfma_f32_16x16x32_bf16(
            al[mi], bh[ni], acc[mi][ni], 0, 0, 0);
      }
  }
}

// D layout: col = lane&15, row = (lane>>4)*4 + reg   [guide-verified]
static __device__ void epilogue1(f32x4 (&acc)[4][4], int bm, int M,
                                 float* __restrict__ Out,
                                 const float* __restrict__ as_vec, float* __restrict__ als,
                                 const float* __restrict__ ad_vec, float* __restrict__ ald) {
  const int tid = threadIdx.x, lane = tid & 63, wv = tid >> 6;
  const int qm = wv >> 1, qn = wv & 1, l15 = lane & 15, l4 = lane >> 4;
#pragma unroll
  for (int mi = 0; mi < 4; ++mi)
#pragma unroll
    for (int ni = 0; ni < 4; ++ni)
#pragma unroll
      for (int r = 0; r < 4; ++r) {
        int grow = bm + qm * 64 + mi * 16 + l4 * 4 + r;
        if (grow < M)
          Out[(size_t)grow * 128 + qn * 64 + ni * 16 + l15] = acc[mi][ni][r];
      }
  float asv[4], adv[4];
#pragma unroll
  for (int ni = 0; ni < 4; ++ni) {
    asv[ni] = as_vec[qn * 64 + ni * 16 + l15];
    adv[ni] = (ald != nullptr) ? ad_vec[qn * 64 + ni * 16 + l15] : 0.f;
  }
#pragma unroll
  for (int mi = 0; mi < 4; ++mi)
#pragma unroll
    for (int r = 0; r < 4; ++r) {
      float s0 = acc[mi][0][r] * asv[0] + acc[mi][1][r] * asv[1];
      float s1 = acc[mi][2][r] * asv[2] + acc[mi][3][r] * asv[3];
      float t0 = acc[mi][0][r] * adv[0] + acc[mi][1][r] * adv[1];
      float t1 = acc[mi][2][r] * adv[2] + acc[mi][3][r] * adv[3];
#pragma unroll
      for (int off = 1; off < 16; off <<= 1) {
        s0 += __shfl_xor(s0, off);
        s1 += __shfl_xor(s1, off);
        t0 += __shfl_xor(t0, off);
        t1 += __shfl_xor(t1, off);
      }
      if (l15 == 0) {
        int grow = bm + qm * 64 + mi * 16 + l4 * 4 + r;
        if (grow < M) {
          als[(size_t)grow * 4 + qn * 2]     = s0;
          als[(size_t)grow * 4 + qn * 2 + 1] = s1;
          if (ald != nullptr) {
            ald[(size_t)grow * 4 + qn * 2]     = t0;
            ald[(size_t)grow * 4 + qn * 2 + 1] = t1;
          }
        }
      }
    }
}

static __device__ void epilogue2(f32x4 (&acc)[4][4], int bm, int M,
                                 const float* __restrict__ A, float* __restrict__ Out,
                                 const float* __restrict__ bt, const float* __restrict__ gv_,
                                 const float* __restrict__ bev, u16* smem) {
  const int tid = threadIdx.x, lane = tid & 63, wv = tid >> 6;
  const int qm = wv >> 1, qn = wv & 1, l15 = lane & 15, l4 = lane >> 4;
  float btv[4], gvv[4], bevv[4];
#pragma unroll
  for (int ni = 0; ni < 4; ++ni) {
    int col = qn * 64 + ni * 16 + l15;
    btv[ni] = bt[col]; gvv[ni] = gv_[col]; bevv[ni] = bev[col];
  }
  float* part = (float*)(smem + 16384);  // reuse W area: [128 rows][2 qn][2]
#pragma unroll
  for (int mi = 0; mi < 4; ++mi)
#pragma unroll
    for (int r = 0; r < 4; ++r) {
      float hs = 0.f, hss = 0.f;
#pragma unroll
      for (int ni = 0; ni < 4; ++ni) {
        float hv = acc[mi][ni][r] + btv[ni];
        hs += hv; hss += hv * hv;
      }
#pragma unroll
      for (int off = 1; off < 16; off <<= 1) {
        hs += __shfl_xor(hs, off);
        hss += __shfl_xor(hss, off);
      }
      if (l15 == 0) {
        int rl = qm * 64 + mi * 16 + l4 * 4 + r;
        part[rl * 4 + qn * 2]     = hs;
        part[rl * 4 + qn * 2 + 1] = hss;
      }
    }
  __syncthreads();
#pragma unroll
  for (int mi = 0; mi < 4; ++mi)
#pragma unroll
    for (int r = 0; r < 4; ++r) {
      int rl = qm * 64 + mi * 16 + l4 * 4 + r;
      int grow = bm + rl;
      float s  = part[rl * 4] + part[rl * 4 + 2];
      float ss = part[rl * 4 + 1] + part[rl * 4 + 3];
      float mu = s * (1.f / 128.f);
      float var = ss * (1.f / 128.f) - mu * mu;
      float rs = rsqrtf(var + 1e-5f);
      if (grow < M) {
#pragma unroll
        for (int ni = 0; ni < 4; ++ni) {
          int col = qn * 64 + ni * 16 + l15;
          float y = A[(size_t)grow * 128 + col];
          float hv = acc[mi][ni][r] + btv[ni];
          float hn = (hv - mu) * rs * gvv[ni] + bevv[ni];
          Out[(size_t)grow * 128 + col] = y + (hn > 0.f ? hn : 0.f);
        }
      }
    }
}

// single-relation GEMM body (MODE1: H+logits, MODE2: transform)
template <int MODE>
static __device__ void gemm_body(int bx, const float* __restrict__ A, int M,
                                 const u16* __restrict__ WT, float* __restrict__ Out,
                                 const float* as_vec, float* als,
                                 const float* ad_vec, float* ald,
                                 const float* bt, const float* gv_, const float* bev,
                                 u16* smem) {
  u16* Ah = smem;
  u16* Al = smem + 8192;
  u16* Wh = smem + 16384;
  u16* Wl = smem + 24576;
  const int tid = threadIdx.x, bm = bx * 128, lane = tid & 63, wv = tid >> 6;
  const int qm = wv >> 1, qn = wv & 1, l15 = lane & 15, l4 = lane >> 4;
  f32x4 acc[4][4];
#pragma unroll
  for (int mi = 0; mi < 4; ++mi)
#pragma unroll
    for (int ni = 0; ni < 4; ++ni) acc[mi][ni] = {0.f, 0.f, 0.f, 0.f};
  for (int kt = 0; kt < 2; ++kt) {
    stage_A(A, M, bm, kt, tid, Ah, Al);
    stage_W(WT, kt, tid, Wh, Wl);
    __syncthreads();
    mfma_tile(Ah, Al, Wh, Wl, qm, qn, l15, l4, acc);
    __syncthreads();
  }
  if (MODE == 1) epilogue1(acc, bm, M, Out, as_vec, als, ad_vec, ald);
  else           epilogue2(acc, bm, M, A, Out, bt, gv_, bev, smem);
}

// dual-relation GEMM body: A staged once, two W images (cc then cio)
static __device__ void gemm_dual_body(int bx, const float* __restrict__ A, int M,
                                      const u16* __restrict__ WT0, const u16* __restrict__ WT1,
                                      float* __restrict__ H0, float* __restrict__ H1,
                                      const float* as0, float* als0,
                                      const float* ad0, float* ald0,
                                      const float* as1, float* als1, u16* smem) {
  u16* Ah = smem;
  u16* Al = smem + 8192;
  u16* Wh = smem + 16384;
  u16* Wl = smem + 24576;
  const int tid = threadIdx.x, bm = bx * 128, lane = tid & 63, wv = tid >> 6;
  const int qm = wv >> 1, qn = wv & 1, l15 = lane & 15, l4 = lane >> 4;
  f32x4 acc0[4][4], acc1[4][4];
#pragma unroll
  for (int mi = 0; mi < 4; ++mi)
#pragma unroll
    for (int ni = 0; ni < 4; ++ni) {
      acc0[mi][ni] = {0.f, 0.f, 0.f, 0.f};
      acc1[mi][ni] = {0.f, 0.f, 0.f, 0.f};
    }
  for (int kt = 0; kt < 2; ++kt) {
    stage_A(A, M, bm, kt, tid, Ah, Al);
    stage_W(WT0, kt, tid, Wh, Wl);
    __syncthreads();
    mfma_tile(Ah, Al, Wh, Wl, qm, qn, l15, l4, acc0);
    __syncthreads();                      // done reading W0
    stage_W(WT1, kt, tid, Wh, Wl);
    __syncthreads();
    mfma_tile(Ah, Al, Wh, Wl, qm, qn, l15, l4, acc1);
    __syncthreads();                      // done reading A + W1 (next kt restages)
  }
  epilogue1(acc0, bm, M, H0, as0, als0, ad0, ald0);
  epilogue1(acc1, bm, M, H1, as1, als1, nullptr, nullptr);
}

// ===== K1: prep_w union zero-counters =======================================
__global__ __launch_bounds__(256) void k1_prep(
    const float* __restrict__ W0, const float* __restrict__ W1,
    const float* __restrict__ W2, const float* __restrict__ W3,
    const float* __restrict__ W4, u16* __restrict__ wt,
    const float* __restrict__ ad_ioc, const float* __restrict__ ad_cio,
    float* __restrict__ Vd_ioc, float* __restrict__ Vd_cio,
    int* __restrict__ cnt_all) {
  int b = blockIdx.x;
  if (b < GB_PREP) {
    int t = b * 256 + threadIdx.x;       // 81920 threads
    int mat = t >> 14, e = t & 16383;
    int k = e >> 7, n = e & 127;
    const float* W = (mat == 0) ? W0 : (mat == 1) ? W1 : (mat == 2) ? W2
                   : (mat == 3) ? W3 : W4;
    float x = W[k * 128 + n];
    u16 h = f2bf(x);
    u16 l = f2bf(x - bf2f(h));
    int kt = k >> 6, kl = k & 63, kg = kl >> 3, j = kl & 7;
    int off = (kt * 128 + n) * 64 + ((kg ^ (n & 7)) * 8) + j;
    u16* base = wt + (size_t)mat * 32768;
    base[off] = h;
    base[16384 + off] = l;
    if (t < 1024) {  // Vd[k,h] = sum_c W[k, h*32+c]*ad[h*32+c]
      const float* Wv = (t < 512) ? W2 : W1;   // ioc then cio
      const float* ad = (t < 512) ? ad_ioc : ad_cio;
      float*       V  = (t < 512) ? Vd_ioc : Vd_cio;
      int i = t & 511, kk = i >> 2, hh = i & 3;
      float s = 0.f;
#pragma unroll
      for (int c = 0; c < 32; ++c) s += Wv[kk * 128 + hh * 32 + c] * ad[hh * 32 + c];
      V[kk * 4 + hh] = s;
    }
  } else {
    int i = (b - GB_PREP) * 256 + threadIdx.x;   // int4 index, 50688 total
    ((int4*)cnt_all)[i] = make_int4(0, 0, 0, 0);
  }
}

// ===== K2a: dual GEMM (cc+cio) union ioc GEMM (64KB-LDS class) ==============
__global__ __launch_bounds__(256) void k2a_gemm(
    const float* __restrict__ x_cell, const float* __restrict__ x_io,
    const u16* __restrict__ WT_cc, const u16* __restrict__ WT_cio,
    const u16* __restrict__ WT_ioc,
    float* __restrict__ Hcc, float* __restrict__ Hcio, float* __restrict__ Hioc,
    const float* __restrict__ as_cc, float* __restrict__ als_cc,
    const float* __restrict__ ad_cc, float* __restrict__ ald_cc,
    const float* __restrict__ as_cio, float* __restrict__ als_cio,
    const float* __restrict__ as_ioc, float* __restrict__ als_ioc) {
  __shared__ u16 smem[32768];
  int b = blockIdx.x;
  if (b < GB_DUAL) {
    gemm_dual_body(b, x_cell, NC, WT_cc, WT_cio, Hcc, Hcio,
                   as_cc, als_cc, ad_cc, ald_cc, as_cio, als_cio, smem);
  } else {
    gemm_body<1>(b - GB_DUAL, x_io, NIO, WT_ioc, Hioc, as_ioc, als_ioc,
                 nullptr, nullptr, nullptr, nullptr, nullptr, smem);
  }
}

// ===== K2b: gemv union hist (no-LDS high-occupancy class) ===================
__global__ __launch_bounds__(256) void k2b_light(
    const float* __restrict__ x_cell, const float* __restrict__ x_io,
    const float* __restrict__ Vd_ioc, const float* __restrict__ Vd_cio,
    float* __restrict__ ald_ioc, float* __restrict__ ald_cio,
    const int* __restrict__ ei_cc, const int* __restrict__ ei_ioc,
    const int* __restrict__ ei_cio,
    int* __restrict__ c_cc, int* __restrict__ c_ioc, int* __restrict__ c_cio) {
  int b = blockIdx.x;
  if (b < GB_GEMV) {
    int lane = threadIdx.x & 63;
    int wid  = (b * 256 + (int)threadIdx.x) >> 6;
    int nw   = GB_GEMV * 4;
    for (int row = wid; row < NC + NIO; row += nw) {
      const float* xr; const float* Vd; float* o;
      if (row < NC) { xr = x_cell + (size_t)row * 128; Vd = Vd_ioc; o = ald_ioc + 4 * (size_t)row; }
      else { int r2 = row - NC; xr = x_io + (size_t)r2 * 128; Vd = Vd_cio; o = ald_cio + 4 * (size_t)r2; }
      float4 v0 = *(const float4*)(Vd + 8 * lane);
      float4 v1 = *(const float4*)(Vd + 8 * lane + 4);
      float2 xv = *(const float2*)(xr + 2 * lane);
      float p0 = xv.x * v0.x + xv.y * v1.x;
      float p1 = xv.x * v0.y + xv.y * v1.y;
      float p2 = xv.x * v0.z + xv.y * v1.z;
      float p3 = xv.x * v0.w + xv.y * v1.w;
#pragma unroll
      for (int off = 32; off >= 1; off >>= 1) {
        p0 += __shfl_xor(p0, off);
        p1 += __shfl_xor(p1, off);
        p2 += __shfl_xor(p2, off);
        p3 += __shfl_xor(p3, off);
      }
      if (lane == 0) *(float4*)o = make_float4(p0, p1, p2, p3);
    }
  } else {
    int i = (b - GB_GEMV) * 256 + threadIdx.x;
    if (i < ECC) atomicAdd(c_cc + ei_cc[ECC + i], 1);
    else if (i < ECC + EIOC) { int j = i - ECC; atomicAdd(c_ioc + ei_ioc[EIOC + j], 1); }
    else if (i < ECC + EIOC + ECIO) { int j = i - ECC - EIOC; atomicAdd(c_cio + ei_cio[ECIO + j], 1); }
  }
}

// ===== K3/K4: device-wide scan (256-thread blocks) ==========================
__global__ __launch_bounds__(256) void scan_p1(const int* __restrict__ cnt,
                                               int* __restrict__ bsum) {
  int b = blockIdx.x, t = threadIdx.x;
  const int4* p = (const int4*)(cnt + (size_t)b * 2048) + t * 2;
  int4 a = p[0], c = p[1];
  int s = a.x + a.y + a.z + a.w + c.x + c.y + c.z + c.w;
#pragma unroll
  for (int off = 1; off < 64; off <<= 1) s += __shfl_xor(s, off);
  __shared__ int ws_[4];
  if ((t & 63) == 0) ws_[t >> 6] = s;
  __syncthreads();
  if (t == 0) bsum[b] = ws_[0] + ws_[1] + ws_[2] + ws_[3];
}

__global__ __launch_bounds__(256) void scan_p3(
    const int* __restrict__ cnt, const int* __restrict__ bsum,
    int* __restrict__ roff_cc, int* __restrict__ wp_cc,
    int* __restrict__ roff_ioc, int* __restrict__ wp_ioc,
    int* __restrict__ roff_cio, int* __restrict__ wp_cio) {
  int b = blockIdx.x, t = threadIdx.x;
  __shared__ int topbase_s;
  __shared__ int wsum[4];
  if (t < 64) {  // exclusive sum of bsum[0..b) (99 <= 128 entries)
    int s = 0;
    if (t < b) s += bsum[t];
    if (t + 64 < b) s += bsum[t + 64];
#pragma unroll
    for (int off = 1; off < 64; off <<= 1) s += __shfl_xor(s, off);
    if (t == 0) topbase_s = s;
  }
  int gbase = b * 2048;
  const int4* p = (const int4*)(cnt + (size_t)gbase) + t * 2;
  int4 a = p[0], c = p[1];
  int cs[8] = {a.x, a.y, a.z, a.w, c.x, c.y, c.z, c.w};
  int s = cs[0] + cs[1] + cs[2] + cs[3] + cs[4] + cs[5] + cs[6] + cs[7];
  int lane = t & 63, wv = t >> 6;
  int inc = s;
#pragma unroll
  for (int off = 1; off < 64; off <<= 1) {
    int u = __shfl_up(inc, off);
    if (lane >= off) inc += u;
  }
  if (lane == 63) wsum[wv] = inc;
  __syncthreads();
  if (t == 0) {
    int run = 0;
#pragma unroll
    for (int i = 0; i < 4; ++i) { int x = wsum[i]; wsum[i] = run; run += x; }
  }
  __syncthreads();
  int excl = inc - s + wsum[wv] + topbase_s;

  int *roff, *wp;
  int rstart, rn, bsub;
  if (b < PAD_CC / 2048) {
    roff = roff_cc;  wp = wp_cc;  rstart = 0;          rn = NC;  bsub = 0;
  } else if (b < 2 * (PAD_CC / 2048)) {
    roff = roff_ioc; wp = wp_ioc; rstart = PAD_CC;     rn = NC;  bsub = ECC;
  } else {
    roff = roff_cio; wp = wp_cio; rstart = 2 * PAD_CC; rn = NIO; bsub = ECC + EIOC;
  }
  int li0 = gbase + t * 8 - rstart;
  int run = excl - bsub;
#pragma unroll
  for (int j = 0; j < 8; ++j) {
    if (li0 + j < rn) { roff[li0 + j] = run; wp[li0 + j] = run; }
    run += cs[j];
  }
  if (b == 0 && t == 0) {
    roff_cc[NC]   = ECC;
    roff_ioc[NC]  = EIOC;
    roff_cio[NIO] = ECIO;
  }
}

// ===== K5: scatter ==========================================================
__global__ void scatter_all(const int* __restrict__ ei_cc, const int* __restrict__ ei_ioc,
                            const int* __restrict__ ei_cio,
                            int* __restrict__ wp_cc, int* __restrict__ wp_ioc,
                            int* __restrict__ wp_cio,
                            int* __restrict__ s_cc, int* __restrict__ s_ioc,
                            int* __restrict__ s_cio) {
  int i = blockIdx.x * blockDim.x + threadIdx.x;
  if (i < ECC) {
    int d = ei_cc[ECC + i];
    s_cc[atomicAdd(wp_cc + d, 1)] = ei_cc[i];
  } else if (i < ECC + EIOC) {
    int j = i - ECC;
    int d = ei_ioc[EIOC + j];
    s_ioc[atomicAdd(wp_ioc + d, 1)] = ei_ioc[j];
  } else if (i < ECC + EIOC + ECIO) {
    int j = i - ECC - EIOC;
    int d = ei_cio[ECIO + j];
    s_cio[atomicAdd(wp_cio + d, 1)] = ei_cio[j];
  }
}

// ===== K6: dest aggregation union ===========================================
static __device__ __forceinline__ float2 gat_contrib(
    int d, int lane, int h,
    const int* __restrict__ roff, const int* __restrict__ ssrc,
    const float* __restrict__ als, const float* __restrict__ ald,
    const float* __restrict__ Hs) {
  int base = roff[d], end = roff[d + 1];
  if (base == end) return make_float2(0.f, 0.f);
  float aldh = ald[4 * (size_t)d + h];
  float acc0 = 0.f, acc1 = 0.f, den = 0.f;
  for (int c0 = base; c0 < end; c0 += 64) {
    int idx  = c0 + lane;
    int my_s = (idx < end) ? ssrc[idx] : 0;
    int cn   = min(64, end - c0);
    for (int j = 0; j < cn; ++j) {
      int s = __shfl(my_s, j);
      float v = als[4 * (size_t)s + h] + aldh;
      v = v > 0.f ? v : 0.2f * v;
      float ex = __expf(v);
      den += ex;
      float2 hv = *(const float2*)(Hs + (size_t)s * 128 + 2 * lane);
      acc0 += ex * hv.x;
      acc1 += ex * hv.y;
    }
  }
  float inv = 1.f / (den + 1e-16f);
  return make_float2(acc0 * inv, acc1 * inv);
}

__global__ __launch_bounds__(256) void k_agg(
    const int* __restrict__ roff1, const int* __restrict__ ssrc1,
    const float* __restrict__ als1, const float* __restrict__ ald1,
    const float* __restrict__ H1, const float* __restrict__ b1,
    const int* __restrict__ roff2, const int* __restrict__ ssrc2,
    const float* __restrict__ als2, const float* __restrict__ ald2,
    const float* __restrict__ H2, const float* __restrict__ b2,
    float* __restrict__ Ycell,
    const int* __restrict__ roff3, const int* __restrict__ ssrc3,
    const float* __restrict__ als3, const float* __restrict__ ald3,
    const float* __restrict__ H3, const float* __restrict__ b3,
    float* __restrict__ Yio) {
  int b = blockIdx.x;
  int lane = threadIdx.x & 63;
  int h    = lane >> 4;
  if (b < GB_AGGC) {
    int wid = (b * 256 + (int)threadIdx.x) >> 6;       // 1 wave per cell dest
    float2 bb1 = *(const float2*)(b1 + 2 * lane);
    float2 bb2 = *(const float2*)(b2 + 2 * lane);
    for (int d = wid; d < NC; d += GB_AGGC * 4) {
      float2 c1 = gat_contrib(d, lane, h, roff1, ssrc1, als1, ald1, H1);
      float2 c2 = gat_contrib(d, lane, h, roff2, ssrc2, als2, ald2, H2);
      *(float2*)(Ycell + (size_t)d * 128 + 2 * lane) =
          make_float2(c1.x + c2.x + bb1.x + bb2.x, c1.y + c2.y + bb1.y + bb2.y);
    }
  } else {
    int wid = ((b - GB_AGGC) * 256 + (int)threadIdx.x) >> 6;
    float2 bb = *(const float2*)(b3 + 2 * lane);
    for (int d = wid; d < NIO; d += GB_AGGI * 4) {
      float2 c = gat_contrib(d, lane, h, roff3, ssrc3, als3, ald3, H3);
      *(float2*)(Yio + (size_t)d * 128 + 2 * lane) = make_float2(c.x + bb.x, c.y + bb.y);
    }
  }
}

// ===== K7: transform union ==================================================
__global__ __launch_bounds__(256) void k_transform(
    const float* __restrict__ Ycell, const u16* __restrict__ WT_tc,
    const float* __restrict__ bt_c, const float* __restrict__ g_c,
    const float* __restrict__ be_c, float* __restrict__ out_cell,
    const float* __restrict__ Yio, const u16* __restrict__ WT_ti,
    const float* __restrict__ bt_i, const float* __restrict__ g_i,
    const float* __restrict__ be_i, float* __restrict__ out_io) {
  __shared__ u16 smem[32768];
  int b = blockIdx.x;
  if (b < GB_TC) {
    gemm_body<2>(b, Ycell, NC, WT_tc, out_cell, nullptr, nullptr, nullptr,
                 nullptr, bt_c, g_c, be_c, smem);
  } else {
    gemm_body<2>(b - GB_TC, Yio, NIO, WT_ti, out_io, nullptr, nullptr, nullptr,
                 nullptr, bt_i, g_i, be_i, smem);
  }
}

// ---------------------------------------------------------------------------
extern "C" void kernel_launch(void* const* d_in, const int* in_sizes, int n_in,
                              void* d_out, int out_size, void* d_ws, size_t ws_size,
                              hipStream_t stream) {
  const float* x_cell = (const float*)d_in[0];
  const float* x_io   = (const float*)d_in[1];
  const int*   ei_cc  = (const int*)d_in[2];
  const int*   ei_cio = (const int*)d_in[3];
  const int*   ei_ioc = (const int*)d_in[4];
  const float* W_cc   = (const float*)d_in[5];
  const float* as_cc  = (const float*)d_in[6];
  const float* ad_cc  = (const float*)d_in[7];
  const float* b_cc   = (const float*)d_in[8];
  const float* W_cio  = (const float*)d_in[9];
  const float* as_cio = (const float*)d_in[10];
  const float* ad_cio = (const float*)d_in[11];
  const float* b_cio  = (const float*)d_in[12];
  const float* W_ioc  = (const float*)d_in[13];
  const float* as_ioc = (const float*)d_in[14];
  const float* ad_ioc = (const float*)d_in[15];
  const float* b_ioc  = (const float*)d_in[16];
  const float* Wt_cell = (const float*)d_in[17];
  const float* bt_cell = (const float*)d_in[18];
  const float* g_cell  = (const float*)d_in[19];
  const float* be_cell = (const float*)d_in[20];
  const float* Wt_io   = (const float*)d_in[21];
  const float* bt_io   = (const float*)d_in[22];
  const float* g_io    = (const float*)d_in[23];
  const float* be_io   = (const float*)d_in[24];

  float* out_cell = (float*)d_out;
  float* out_io   = (float*)d_out + (size_t)NC * 128;

  // ----- workspace layout (identical to R8/R9) -----
  float* w = (float*)d_ws;
  size_t o = 0;
  float* Hcc     = w + o; o += (size_t)NC * 128;
  float* Hcio    = w + o; o += (size_t)NC * 128;
  float* Hioc    = w + o; o += (size_t)NIO * 128;
  float* Ycell   = w + o; o += (size_t)NC * 128;
  float* Yio     = w + o; o += (size_t)NIO * 128;
  float* als_cc  = w + o; o += (size_t)NC * 4;
  float* ald_cc  = w + o; o += (size_t)NC * 4;
  float* als_cio = w + o; o += (size_t)NC * 4;
  float* ald_ioc = w + o; o += (size_t)NC * 4;
  float* als_ioc = w + o; o += (size_t)NIO * 4;
  float* ald_cio = w + o; o += (size_t)NIO * 4;
  float* Vd_ioc  = w + o; o += 512;
  float* Vd_cio  = w + o; o += 512;
  u16* wt_base   = (u16*)(w + o); o += 81920;   // 5 mats x 32768 u16 (hi|lo)
  int* ib = (int*)(w + o);
  size_t io_ = 0;
  int* cnt_all  = ib + io_; io_ += NTOT_PAD;
  int* cnt_cc   = cnt_all;
  int* cnt_ioc  = cnt_all + PAD_CC;
  int* cnt_cio  = cnt_all + 2 * PAD_CC;
  int* bsum     = ib + io_; io_ += 128;
  int* roff_cc  = ib + io_; io_ += NC + 1;
  int* wp_cc    = ib + io_; io_ += NC;
  int* roff_ioc = ib + io_; io_ += NC + 1;
  int* wp_ioc   = ib + io_; io_ += NC;
  int* roff_cio = ib + io_; io_ += NIO + 1;
  int* wp_cio   = ib + io_; io_ += NIO;
  int* ssrc_cc  = ib + io_; io_ += ECC;
  int* ssrc_ioc = ib + io_; io_ += EIOC;
  int* ssrc_cio = ib + io_; io_ += ECIO;

  u16* WT_cc  = wt_base;
  u16* WT_cio = wt_base + 32768;
  u16* WT_ioc = wt_base + 2 * 32768;
  u16* WT_tc  = wt_base + 3 * 32768;
  u16* WT_ti  = wt_base + 4 * 32768;

  // K1: W prep + Vd + counter zeroing
  k1_prep<<<GB_PREP + GB_ZERO, 256, 0, stream>>>(
      W_cc, W_cio, W_ioc, Wt_cell, Wt_io, wt_base,
      ad_ioc, ad_cio, Vd_ioc, Vd_cio, cnt_all);

  // K2a: dual GEMM (cc+cio) || ioc GEMM   (64KB-LDS resource class)
  k2a_gemm<<<GB_DUAL + GB_IOC, 256, 0, stream>>>(
      x_cell, x_io, WT_cc, WT_cio, WT_ioc, Hcc, Hcio, Hioc,
      as_cc, als_cc, ad_cc, ald_cc, as_cio, als_cio, as_ioc, als_ioc);

  // K2b: gemv || hist   (no-LDS high-occupancy class)
  k2b_light<<<GB_GEMV + GB_HIST, 256, 0, stream>>>(
      x_cell, x_io, Vd_ioc, Vd_cio, ald_ioc, ald_cio,
      ei_cc, ei_ioc, ei_cio, cnt_cc, cnt_ioc, cnt_cio);

  // K3/K4: device-wide scan
  scan_p1<<<SCAN_NBLK, 256, 0, stream>>>(cnt_all, bsum);
  scan_p3<<<SCAN_NBLK, 256, 0, stream>>>(cnt_all, bsum, roff_cc, wp_cc,
                                         roff_ioc, wp_ioc, roff_cio, wp_cio);

  // K5: scatter
  scatter_all<<<GB_HIST, 256, 0, stream>>>(
      ei_cc, ei_ioc, ei_cio, wp_cc, wp_ioc, wp_cio, ssrc_cc, ssrc_ioc, ssrc_cio);

  // K6: per-dest aggregation (cell || io)
  k_agg<<<GB_AGGC + GB_AGGI, 256, 0, stream>>>(
      roff_cc, ssrc_cc, als_cc, ald_cc, Hcc, b_cc,
      roff_ioc, ssrc_ioc, als_ioc, ald_ioc, Hioc, b_ioc, Ycell,
      roff_cio, ssrc_cio, als_cio, ald_cio, Hcio, b_cio, Yio);

  // K7: transform (cell || io) into d_out
  k_transform<<<GB_TC + GB_TI, 256, 0, stream>>>(
      Ycell, WT_tc, bt_cell, g_cell, be_cell, out_cell,
      Yio, WT_ti, bt_io, g_io, be_io, out_io);
}